// Round 1
// baseline (8229.163 us; speedup 1.0000x reference)
//
#include <hip/hip_runtime.h>
#include <hip/hip_bf16.h>
#include <math.h>

#define DIMD 256
#define ROWS_PER_BLOCK 32
#define BLOCK_THREADS 512
#define KSTEPS 26
// log2(e) / TEMP, TEMP = 0.2
#define EXP_C 7.2134752f
// 1 / (1 - P), P = 0.1
#define INV_1MP 1.1111112f

// Fused: mask GEMM -> E = exp((mask - rowmax)/T) -> 26 peeling steps on z = 1-y
// -> out = feature * z / 0.9.
// Layout: 512 threads = 8 waves; thread owns row r = tid>>4 (32 rows/block) and
// 16 columns c_j = (tid&15) + 16*j. Row reductions = tree over 16 j's + 4-level
// __shfl_xor butterfly across the 16 lanes of a row group (aligned to 16).
__global__ __launch_bounds__(BLOCK_THREADS, 4)
void sad_fused_kernel(const float* __restrict__ feat,
                      const float* __restrict__ W,
                      const float* __restrict__ bias,
                      float* __restrict__ out,
                      int N)
{
    // 32 rows x 260 floats (65 float4) -- +1 float4 pad breaks bank aliasing
    __shared__ float4 ldsf[ROWS_PER_BLOCK * 65];

    const int tid = threadIdx.x;
    const int lr  = tid & 15;   // lane within row group
    const int r   = tid >> 4;   // row within block (0..31)
    const long long n0 = (long long)blockIdx.x * ROWS_PER_BLOCK;

    // ---- stage 32 feature rows into LDS (coalesced 1KB/wave-instr) ----
    const float4* fv = (const float4*)feat;
    #pragma unroll
    for (int i = 0; i < 4; ++i) {
        int F = i * BLOCK_THREADS + tid;      // 0..2047
        int row = F >> 6, c4 = F & 63;
        long long grow = n0 + row;
        if (grow >= N) grow = N - 1;          // clamp (N%32==0 in practice)
        ldsf[row * 65 + c4] = fv[grow * 64 + c4];
    }
    __syncthreads();

    // ---- GEMM phase: acc[j] = b[c_j] + dot(f[r,:], W[c_j,:]) ----
    float acc[16];
    #pragma unroll
    for (int j = 0; j < 16; ++j) acc[j] = bias[lr + 16 * j];

    const float4* Wv = (const float4*)W;
    const float4* fr = &ldsf[r * 65];
    #pragma unroll 2
    for (int k4 = 0; k4 < 64; ++k4) {
        float4 f4 = fr[k4];                   // broadcast across 16 lanes
        #pragma unroll
        for (int j = 0; j < 16; ++j) {
            float4 w4 = Wv[(lr + 16 * j) * 64 + k4];
            acc[j] = fmaf(f4.x, w4.x, acc[j]);
            acc[j] = fmaf(f4.y, w4.y, acc[j]);
            acc[j] = fmaf(f4.z, w4.z, acc[j]);
            acc[j] = fmaf(f4.w, w4.w, acc[j]);
        }
    }

    // ---- row max (tree over j, butterfly over 16 lanes) ----
    float m01, m23, M;
    {
        float a0 = fmaxf(acc[0], acc[1]),  a1 = fmaxf(acc[2], acc[3]);
        float a2 = fmaxf(acc[4], acc[5]),  a3 = fmaxf(acc[6], acc[7]);
        float a4 = fmaxf(acc[8], acc[9]),  a5 = fmaxf(acc[10], acc[11]);
        float a6 = fmaxf(acc[12], acc[13]), a7 = fmaxf(acc[14], acc[15]);
        m01 = fmaxf(fmaxf(a0, a1), fmaxf(a2, a3));
        m23 = fmaxf(fmaxf(a4, a5), fmaxf(a6, a7));
        M = fmaxf(m01, m23);
    }
    #pragma unroll
    for (int d = 1; d < 16; d <<= 1) M = fmaxf(M, __shfl_xor(M, d));

    // ---- E = exp2((mask - M) * log2e/T); z = 1 ----
    float E[16], z[16];
    #pragma unroll
    for (int j = 0; j < 16; ++j) {
        E[j] = __builtin_amdgcn_exp2f((acc[j] - M) * EXP_C);
        z[j] = 1.0f;
    }

    // ---- 26 peeling steps: t = E*z^5; S = sum(t); z -= (t/S)*z ----
    for (int it = 0; it < KSTEPS; ++it) {
        float t[16];
        #pragma unroll
        for (int j = 0; j < 16; ++j) {
            float z2 = z[j] * z[j];
            float z4 = z2 * z2;
            float z5 = z4 * z[j];
            t[j] = E[j] * z5;
        }
        // tree sum over the 16 owned elements (depth 4)
        float s0 = (t[0] + t[1]) + (t[2] + t[3]);
        float s1 = (t[4] + t[5]) + (t[6] + t[7]);
        float s2 = (t[8] + t[9]) + (t[10] + t[11]);
        float s3 = (t[12] + t[13]) + (t[14] + t[15]);
        float s = (s0 + s1) + (s2 + s3);
        #pragma unroll
        for (int d = 1; d < 16; d <<= 1) s += __shfl_xor(s, d);
        float rinv = (s > 0.f) ? __builtin_amdgcn_rcpf(s) : 0.f;
        float nr = -rinv;
        #pragma unroll
        for (int j = 0; j < 16; ++j) {
            z[j] = fmaf(t[j] * z[j], nr, z[j]);   // z -= E*z^6 / S
        }
    }

    // ---- out = f * z / (1-P) ----
    if (n0 + r < N) {
        const float* fs = (const float*)ldsf;
        float* orow = out + (n0 + r) * DIMD;
        #pragma unroll
        for (int j = 0; j < 16; ++j) {
            int c = lr + 16 * j;
            orow[c] = fs[r * 260 + c] * (z[j] * INV_1MP);
        }
    }
}

extern "C" void kernel_launch(void* const* d_in, const int* in_sizes, int n_in,
                              void* d_out, int out_size, void* d_ws, size_t ws_size,
                              hipStream_t stream) {
    const float* feat = (const float*)d_in[0];
    const float* W    = (const float*)d_in[1];
    const float* bias = (const float*)d_in[2];
    float* out = (float*)d_out;
    int N = in_sizes[0] / DIMD;
    int grid = (N + ROWS_PER_BLOCK - 1) / ROWS_PER_BLOCK;
    sad_fused_kernel<<<grid, BLOCK_THREADS, 0, stream>>>(feat, W, bias, out, N);
}

// Round 2
// 594.642 us; speedup vs baseline: 13.8389x; 13.8389x over previous
//
#include <hip/hip_runtime.h>
#include <hip/hip_bf16.h>
#include <math.h>

typedef __bf16 bf16x8 __attribute__((ext_vector_type(8)));
typedef __bf16 bf16x4 __attribute__((ext_vector_type(4)));
typedef float  f32x4  __attribute__((ext_vector_type(4)));

#define DIMD    256
#define MT      64          // rows per block
#define BT      256         // threads per block (4 waves, each owns 16 rows x 256 cols)
#define KSTEPS  26
#define EXP_C   7.2134752044448170f   // log2(e)/TEMP, TEMP=0.2
#define INV_1MP 1.1111111111111112f   // 1/(1-P), P=0.1

// ---------------- pre-kernel: W[c][k] fp32 -> frag-major bf16 hi/lo in ws ----
// Tile (kt,ct): 64 lanes x 8 bf16 (16B/lane). Lane l covers col=ct*16+(l&15),
// k = kt*32 + (l>>4)*8 .. +7  (matches mfma_f32_16x16x32_bf16 B-frag layout).
// ws: [128 tiles][64 lanes] hi  then  [128][64] lo  (256 KB total).
__global__ __launch_bounds__(256)
void w_conv_kernel(const float* __restrict__ W, bf16x8* __restrict__ ws) {
    int gid  = blockIdx.x * 256 + threadIdx.x;   // 0..8191
    int tile = gid >> 6;                         // kt*16+ct
    int lane = gid & 63;
    int kt = tile >> 4, ct = tile & 15;
    int col = ct * 16 + (lane & 15);
    int k0  = kt * 32 + (lane >> 4) * 8;
    const float* wr = W + col * 256 + k0;
    float4 f01 = *(const float4*)wr;
    float4 f23 = *(const float4*)(wr + 4);
    float wv[8] = {f01.x, f01.y, f01.z, f01.w, f23.x, f23.y, f23.z, f23.w};
    bf16x8 hi, lo;
    #pragma unroll
    for (int j = 0; j < 8; ++j) {
        __bf16 h = (__bf16)wv[j];
        hi[j] = h;
        lo[j] = (__bf16)(wv[j] - (float)h);
    }
    ws[tile * 64 + lane]        = hi;
    ws[8192 + tile * 64 + lane] = lo;
}

// ---------------- main fused kernel --------------------------------------
// LDS: A_hi[64][256] bf16 (32KB) + A_lo (32KB), byte-XOR swizzle
// byte = row*512 + ((k*2) ^ ((row&7)<<4)) within each plane.
__global__ __launch_bounds__(BT, 2)
void sad_mfma_kernel(const float* __restrict__ feat,
                     const float* __restrict__ bias,
                     const bf16x8* __restrict__ ws,
                     float* __restrict__ out,
                     int N)
{
    __shared__ __align__(16) unsigned char smem[MT * 512 * 2];  // 64 KB

    const int tid  = threadIdx.x;
    const int lane = tid & 63;
    const int wv   = tid >> 6;           // wave 0..3, owns rows wv*16..wv*16+15
    const long long n0 = (long long)blockIdx.x * MT;

    // ---- stage 64 feature rows -> bf16 hi/lo LDS (swizzled) ----
    const float4* fvec = (const float4*)feat;
    #pragma unroll
    for (int i = 0; i < 16; ++i) {
        int flat4 = i * BT + tid;            // float4 index over [64 rows][64 f4]
        int row = flat4 >> 6;
        int c4  = flat4 & 63;
        long long grow = n0 + row;
        if (grow >= N) grow = N - 1;
        float4 f = fvec[grow * 64 + c4];
        float fx[4] = {f.x, f.y, f.z, f.w};
        bf16x4 h4, l4;
        #pragma unroll
        for (int j = 0; j < 4; ++j) {
            __bf16 h = (__bf16)fx[j];
            h4[j] = h;
            l4[j] = (__bf16)(fx[j] - (float)h);
        }
        int off = row * 512 + ((c4 * 8) ^ ((row & 7) << 4));
        *(bf16x4*)(smem + off)         = h4;
        *(bf16x4*)(smem + 32768 + off) = l4;
    }
    __syncthreads();

    // ---- GEMM: wave wv computes mask rows [wv*16, wv*16+16) x all 256 cols ----
    // acc[ct][p]: col = ct*16 + (lane&15), row = wv*16 + (lane>>4)*4 + p
    f32x4 acc[16];
    #pragma unroll
    for (int ct = 0; ct < 16; ++ct) {
        float b = bias[ct * 16 + (lane & 15)];
        acc[ct] = f32x4{b, b, b, b};
    }

    const int arow  = wv * 16 + (lane & 15);       // A-frag row for this lane
    const int swzA  = (arow & 7) << 4;
    const int abase = arow * 512;
    const int kgrp  = (lane >> 4) * 16;            // k-byte subgroup offset

    #pragma unroll
    for (int kt = 0; kt < 8; ++kt) {
        int kbyte = kt * 64 + kgrp;
        bf16x8 ah = *(const bf16x8*)(smem + abase + (kbyte ^ swzA));
        bf16x8 al = *(const bf16x8*)(smem + 32768 + abase + (kbyte ^ swzA));
        #pragma unroll
        for (int ct = 0; ct < 16; ++ct) {
            bf16x8 bh = ws[(kt * 16 + ct) * 64 + lane];
            bf16x8 bl = ws[8192 + (kt * 16 + ct) * 64 + lane];
            acc[ct] = __builtin_amdgcn_mfma_f32_16x16x32_bf16(ah, bh, acc[ct], 0, 0, 0);
            acc[ct] = __builtin_amdgcn_mfma_f32_16x16x32_bf16(ah, bl, acc[ct], 0, 0, 0);
            acc[ct] = __builtin_amdgcn_mfma_f32_16x16x32_bf16(al, bh, acc[ct], 0, 0, 0);
        }
    }

    // ---- row max (per plane p): in-thread over 16 cts + 16-lane butterfly ----
    float M[4];
    #pragma unroll
    for (int p = 0; p < 4; ++p) {
        float m = acc[0][p];
        #pragma unroll
        for (int ct = 1; ct < 16; ++ct) m = fmaxf(m, acc[ct][p]);
        #pragma unroll
        for (int d = 1; d < 16; d <<= 1) m = fmaxf(m, __shfl_xor(m, d));
        M[p] = m;
    }

    // ---- E = exp2((mask - M)*C); z = 1 ----
    f32x4 E[16], z[16];
    #pragma unroll
    for (int ct = 0; ct < 16; ++ct) {
        #pragma unroll
        for (int p = 0; p < 4; ++p) {
            E[ct][p] = __builtin_amdgcn_exp2f((acc[ct][p] - M[p]) * EXP_C);
            z[ct][p] = 1.0f;
        }
    }

    // ---- 26 peeling steps, fully in registers ----
    for (int it = 0; it < KSTEPS; ++it) {
        #pragma unroll
        for (int p = 0; p < 4; ++p) {
            float t[16];
            #pragma unroll
            for (int ct = 0; ct < 16; ++ct) {
                float zz = z[ct][p];
                float z2 = zz * zz;
                float z4 = z2 * z2;
                t[ct] = E[ct][p] * (z4 * zz);      // E * z^5
            }
            float s0 = (t[0] + t[1]) + (t[2] + t[3]);
            float s1 = (t[4] + t[5]) + (t[6] + t[7]);
            float s2 = (t[8] + t[9]) + (t[10] + t[11]);
            float s3 = (t[12] + t[13]) + (t[14] + t[15]);
            float s  = (s0 + s1) + (s2 + s3);
            #pragma unroll
            for (int d = 1; d < 16; d <<= 1) s += __shfl_xor(s, d);
            float rinv = (s > 0.0f) ? __builtin_amdgcn_rcpf(s) : 0.0f;
            float nr = -rinv;
            #pragma unroll
            for (int ct = 0; ct < 16; ++ct) {
                z[ct][p] = fmaf(t[ct] * z[ct][p], nr, z[ct][p]);  // z -= E*z^6/S
            }
        }
    }

    // ---- out = f * z / (1-P): f = hi+lo from LDS ----
    #pragma unroll
    for (int p = 0; p < 4; ++p) {
        int row = wv * 16 + (lane >> 4) * 4 + p;
        long long grow = n0 + row;
        if (grow < N) {
            int swz = (row & 7) << 4;
            #pragma unroll
            for (int ct = 0; ct < 16; ++ct) {
                int col = ct * 16 + (lane & 15);
                int off = row * 512 + ((col * 2) ^ swz);
                float fval = (float)(*(const __bf16*)(smem + off))
                           + (float)(*(const __bf16*)(smem + 32768 + off));
                out[grow * 256 + col] = fval * (z[ct][p] * INV_1MP);
            }
        }
    }
}

extern "C" void kernel_launch(void* const* d_in, const int* in_sizes, int n_in,
                              void* d_out, int out_size, void* d_ws, size_t ws_size,
                              hipStream_t stream) {
    const float* feat = (const float*)d_in[0];
    const float* W    = (const float*)d_in[1];
    const float* bias = (const float*)d_in[2];
    float* out = (float*)d_out;
    int N = in_sizes[0] / DIMD;

    // 1) convert W -> frag-major bf16 hi/lo in workspace (256 KB)
    w_conv_kernel<<<32, 256, 0, stream>>>(W, (bf16x8*)d_ws);

    // 2) fused mask-GEMM + 26-step peeling + output
    int grid = (int)((N + MT - 1) / MT);
    sad_mfma_kernel<<<grid, BT, 0, stream>>>(feat, bias, (const bf16x8*)d_ws, out, N);
}

// Round 3
// 468.709 us; speedup vs baseline: 17.5571x; 1.2687x over previous
//
#include <hip/hip_runtime.h>
#include <hip/hip_bf16.h>
#include <math.h>

typedef _Float16 f16x8 __attribute__((ext_vector_type(8)));
typedef _Float16 f16x4 __attribute__((ext_vector_type(4)));
typedef float    f32x4 __attribute__((ext_vector_type(4)));
typedef float    f32x2 __attribute__((ext_vector_type(2)));

#define DIMD    256
#define MT      64          // rows per block
#define BT      256         // 4 waves; each wave owns 16 rows x 256 cols
#define KSTEPS  26
#define EXP_C   7.2134752044448170f   // log2(e)/TEMP, TEMP=0.2
#define INV_1MP 1.1111111111111112f   // 1/(1-P), P=0.1

// ---- pre-kernel: W[c][k] fp32 -> frag-major fp16 hi/lo --------------------
// Tile (kt,ct): 64 lanes x 8 fp16 (16B/lane). Lane l: col=ct*16+(l&15),
// k = kt*32 + (l>>4)*8 .. +7  (mfma_f32_16x16x32_f16 B-frag layout).
// ws: [128 tiles][64 lanes] hi, then [128][64] lo (256 KB total).
__global__ __launch_bounds__(256)
void w_conv_kernel(const float* __restrict__ W, f16x8* __restrict__ ws) {
    int gid  = blockIdx.x * 256 + threadIdx.x;   // 0..8191
    int tile = gid >> 6;                         // kt*16+ct
    int lane = gid & 63;
    int kt = tile >> 4, ct = tile & 15;
    int col = ct * 16 + (lane & 15);
    int k0  = kt * 32 + (lane >> 4) * 8;
    const float* wr = W + col * 256 + k0;
    float4 f01 = *(const float4*)wr;
    float4 f23 = *(const float4*)(wr + 4);
    float wv[8] = {f01.x, f01.y, f01.z, f01.w, f23.x, f23.y, f23.z, f23.w};
    f16x8 hi, lo;
    #pragma unroll
    for (int j = 0; j < 8; ++j) {
        _Float16 h = (_Float16)wv[j];
        hi[j] = h;
        lo[j] = (_Float16)(wv[j] - (float)h);
    }
    ws[tile * 64 + lane]        = hi;
    ws[8192 + tile * 64 + lane] = lo;
}

// ---- main fused kernel ----------------------------------------------------
// LDS: A fp16 [64 rows][256 cols], 32 KB, byte-XOR swizzle
//   byte = row*512 + ((col*2) ^ ((row&7)<<4))
__global__ __launch_bounds__(BT, 3)
void sad_mfma_kernel(const float* __restrict__ feat,
                     const float* __restrict__ bias,
                     const f16x8* __restrict__ ws,
                     float* __restrict__ out,
                     int N)
{
    __shared__ __align__(16) unsigned char smem[MT * 512];  // 32 KB

    const int tid  = threadIdx.x;
    const int lane = tid & 63;
    const int wv   = tid >> 6;           // wave 0..3, owns rows wv*16..+15
    const long long n0 = (long long)blockIdx.x * MT;

    // ---- stage 64 feature rows -> fp16 LDS (swizzled) ----
    const float4* fvec = (const float4*)feat;
    #pragma unroll
    for (int i = 0; i < 16; ++i) {
        int flat4 = i * BT + tid;            // float4 index over [64 rows][64 f4]
        int row = flat4 >> 6;
        int c4  = flat4 & 63;
        long long grow = n0 + row;
        if (grow >= N) grow = N - 1;
        float4 f = fvec[grow * 64 + c4];
        f16x4 h4;
        h4[0] = (_Float16)f.x; h4[1] = (_Float16)f.y;
        h4[2] = (_Float16)f.z; h4[3] = (_Float16)f.w;
        int off = row * 512 + ((c4 * 8) ^ ((row & 7) << 4));
        *(f16x4*)(smem + off) = h4;
    }
    __syncthreads();

    // ---- GEMM: acc[ct][p] -> col = ct*16+(lane&15), row = wv*16+(lane>>4)*4+p
    f32x4 acc[16];
    #pragma unroll
    for (int ct = 0; ct < 16; ++ct) {
        float b = bias[ct * 16 + (lane & 15)];
        acc[ct] = f32x4{b, b, b, b};
    }

    const int arow  = wv * 16 + (lane & 15);
    const int swzA  = (arow & 7) << 4;
    const int abase = arow * 512;
    const int kgrp  = (lane >> 4) * 16;

    #pragma unroll
    for (int kt = 0; kt < 8; ++kt) {
        int kbyte = kt * 64 + kgrp;
        f16x8 a8 = *(const f16x8*)(smem + abase + (kbyte ^ swzA));
        #pragma unroll
        for (int ct = 0; ct < 16; ++ct) {
            f16x8 bh = ws[(kt * 16 + ct) * 64 + lane];
            f16x8 bl = ws[8192 + (kt * 16 + ct) * 64 + lane];
            acc[ct] = __builtin_amdgcn_mfma_f32_16x16x32_f16(a8, bh, acc[ct], 0, 0, 0);
            acc[ct] = __builtin_amdgcn_mfma_f32_16x16x32_f16(a8, bl, acc[ct], 0, 0, 0);
        }
    }

    // ---- row max per plane: 16 cts in-thread + 16-lane butterfly ----
    float M[4];
    #pragma unroll
    for (int p = 0; p < 4; ++p) {
        float m = acc[0][p];
        #pragma unroll
        for (int ct = 1; ct < 16; ++ct) m = fmaxf(m, acc[ct][p]);
        #pragma unroll
        for (int d = 1; d < 16; d <<= 1) m = fmaxf(m, __shfl_xor(m, d));
        M[p] = m;
    }

    // ---- E = exp2((mask-M)*C), packed in f32x2 pairs over ct; z = 1 ----
    f32x2 E2[8][4], z2[8][4];
    #pragma unroll
    for (int cc = 0; cc < 8; ++cc) {
        #pragma unroll
        for (int p = 0; p < 4; ++p) {
            E2[cc][p] = f32x2{
                __builtin_amdgcn_exp2f((acc[2 * cc][p]     - M[p]) * EXP_C),
                __builtin_amdgcn_exp2f((acc[2 * cc + 1][p] - M[p]) * EXP_C)};
            z2[cc][p] = f32x2{1.0f, 1.0f};
        }
    }

    // ---- 26 peeling steps: t=E*z^5; S=sum(t); z -= (t/S)*z  (packed f32) ----
    #pragma unroll 1
    for (int it = 0; it < KSTEPS; ++it) {
        #pragma unroll
        for (int p = 0; p < 4; ++p) {
            f32x2 t2[8];
            #pragma unroll
            for (int cc = 0; cc < 8; ++cc) {
                f32x2 zz = z2[cc][p];
                f32x2 a  = zz * zz;      // z^2
                f32x2 b  = a * a;        // z^4
                t2[cc] = E2[cc][p] * (b * zz);   // E*z^5
            }
            f32x2 s01 = (t2[0] + t2[1]) + (t2[2] + t2[3]);
            f32x2 s23 = (t2[4] + t2[5]) + (t2[6] + t2[7]);
            f32x2 sv  = s01 + s23;
            float s   = sv.x + sv.y;
            #pragma unroll
            for (int d = 1; d < 16; d <<= 1) s += __shfl_xor(s, d);
            float rinv = (s > 0.0f) ? __builtin_amdgcn_rcpf(s) : 0.0f;
            f32x2 nr2  = f32x2{-rinv, -rinv};
            #pragma unroll
            for (int cc = 0; cc < 8; ++cc) {
                z2[cc][p] = __builtin_elementwise_fma(t2[cc] * z2[cc][p], nr2, z2[cc][p]);
            }
        }
    }

    // ---- out = f * z / (1-P): f from fp16 LDS plane ----
    #pragma unroll
    for (int p = 0; p < 4; ++p) {
        int row = wv * 16 + (lane >> 4) * 4 + p;
        long long grow = n0 + row;
        if (grow < N) {
            int swz = (row & 7) << 4;
            #pragma unroll
            for (int ct = 0; ct < 16; ++ct) {
                int col = ct * 16 + (lane & 15);
                int off = row * 512 + ((col * 2) ^ swz);
                float fval = (float)(*(const _Float16*)(smem + off));
                float zv = (ct & 1) ? z2[ct >> 1][p].y : z2[ct >> 1][p].x;
                out[grow * 256 + col] = fval * (zv * INV_1MP);
            }
        }
    }
}

extern "C" void kernel_launch(void* const* d_in, const int* in_sizes, int n_in,
                              void* d_out, int out_size, void* d_ws, size_t ws_size,
                              hipStream_t stream) {
    const float* feat = (const float*)d_in[0];
    const float* W    = (const float*)d_in[1];
    const float* bias = (const float*)d_in[2];
    float* out = (float*)d_out;
    int N = in_sizes[0] / DIMD;

    // 1) W -> frag-major fp16 hi/lo in workspace (256 KB)
    w_conv_kernel<<<32, 256, 0, stream>>>(W, (f16x8*)d_ws);

    // 2) fused mask-GEMM + 26-step peeling + output
    int grid = (int)((N + MT - 1) / MT);
    sad_mfma_kernel<<<grid, BT, 0, stream>>>(feat, bias, (const f16x8*)d_ws, out, N);
}

// Round 4
// 459.556 us; speedup vs baseline: 17.9068x; 1.0199x over previous
//
#include <hip/hip_runtime.h>
#include <hip/hip_bf16.h>
#include <math.h>

typedef _Float16 f16x8 __attribute__((ext_vector_type(8)));
typedef _Float16 f16x4 __attribute__((ext_vector_type(4)));
typedef _Float16 f16x2 __attribute__((ext_vector_type(2)));
typedef float    f32x4 __attribute__((ext_vector_type(4)));
typedef float    f32x2 __attribute__((ext_vector_type(2)));

#define DIMD    256
#define MT      64          // rows per block
#define BT      256         // 4 waves; each wave owns 16 rows x 256 cols
#define KSTEPS  26
#define EXP_C   7.2134752044448170f   // log2(e)/TEMP, TEMP=0.2
#define LOG2E   1.4426950408889634f   // = EXP_C * TEMP (le5 = le/5)
#define INV_1MP 1.1111111111111112f   // 1/(1-P), P=0.1

// ---- packed-f32 VALU helpers (VOP3P, 2x f32 per instruction) -------------
static __device__ __forceinline__ f32x2 pk_fma(f32x2 a, f32x2 b, f32x2 c) {
    f32x2 d;
    asm("v_pk_fma_f32 %0, %1, %2, %3" : "=v"(d) : "v"(a), "v"(b), "v"(c));
    return d;
}
static __device__ __forceinline__ f32x2 pk_mul(f32x2 a, f32x2 b) {
    f32x2 d;
    asm("v_pk_mul_f32 %0, %1, %2" : "=v"(d) : "v"(a), "v"(b));
    return d;
}
static __device__ __forceinline__ f32x2 pk_add(f32x2 a, f32x2 b) {
    f32x2 d;
    asm("v_pk_add_f32 %0, %1, %2" : "=v"(d) : "v"(a), "v"(b));
    return d;
}

// ---- DPP row_ror cross-lane (16-lane groups, no DS ops) ------------------
template<int CTRL>
static __device__ __forceinline__ float dpp_ror(float s) {
    return __builtin_bit_cast(float, __builtin_amdgcn_update_dpp(
        0, __builtin_bit_cast(int, s), CTRL, 0xf, 0xf, false));
}
static __device__ __forceinline__ float row16_sum(float s) {
    s += dpp_ror<0x128>(s);   // ror:8
    s += dpp_ror<0x124>(s);   // ror:4
    s += dpp_ror<0x122>(s);   // ror:2
    s += dpp_ror<0x121>(s);   // ror:1
    return s;
}
static __device__ __forceinline__ float row16_max(float m) {
    m = fmaxf(m, dpp_ror<0x128>(m));
    m = fmaxf(m, dpp_ror<0x124>(m));
    m = fmaxf(m, dpp_ror<0x122>(m));
    m = fmaxf(m, dpp_ror<0x121>(m));
    return m;
}

// ---- pre-kernel: W[c][k] fp32 -> frag-major fp16 hi/lo --------------------
// Tile (kt,ct): 64 lanes x 8 fp16. Lane l: col=ct*16+(l&15), k=kt*32+(l>>4)*8..+7
__global__ __launch_bounds__(256)
void w_conv_kernel(const float* __restrict__ W, f16x8* __restrict__ ws) {
    int gid  = blockIdx.x * 256 + threadIdx.x;   // 0..8191
    int tile = gid >> 6;                         // kt*16+ct
    int lane = gid & 63;
    int kt = tile >> 4, ct = tile & 15;
    int col = ct * 16 + (lane & 15);
    int k0  = kt * 32 + (lane >> 4) * 8;
    const float* wr = W + col * 256 + k0;
    float4 f01 = *(const float4*)wr;
    float4 f23 = *(const float4*)(wr + 4);
    float wv[8] = {f01.x, f01.y, f01.z, f01.w, f23.x, f23.y, f23.z, f23.w};
    f16x8 hi, lo;
    #pragma unroll
    for (int j = 0; j < 8; ++j) {
        _Float16 h = (_Float16)wv[j];
        hi[j] = h;
        lo[j] = (_Float16)(wv[j] - (float)h);
    }
    ws[tile * 64 + lane]        = hi;
    ws[8192 + tile * 64 + lane] = lo;
}

// ---- main fused kernel ----------------------------------------------------
// LDS: A fp16 [64 rows][256 cols], 32 KB, byte-XOR swizzle:
//   byte = row*512 + ((col*2) ^ ((row&7)<<4))
__global__ __launch_bounds__(BT, 4)
void sad_mfma_kernel(const float* __restrict__ feat,
                     const float* __restrict__ bias,
                     const f16x8* __restrict__ ws,
                     float* __restrict__ out,
                     int N)
{
    __shared__ __align__(16) unsigned char smem[MT * 512];  // 32 KB

    const int tid  = threadIdx.x;
    const int lane = tid & 63;
    const int wv   = tid >> 6;           // wave 0..3, owns rows wv*16..+15
    const long long n0 = (long long)blockIdx.x * MT;

    // ---- stage 64 feature rows -> fp16 LDS (swizzled) ----
    const float4* fvec = (const float4*)feat;
    #pragma unroll
    for (int i = 0; i < 16; ++i) {
        int flat4 = i * BT + tid;            // float4 index over [64 rows][64 f4]
        int row = flat4 >> 6;
        int c4  = flat4 & 63;
        long long grow = n0 + row;
        if (grow >= N) grow = N - 1;
        float4 f = fvec[grow * 64 + c4];
        f16x4 h4;
        h4[0] = (_Float16)f.x; h4[1] = (_Float16)f.y;
        h4[2] = (_Float16)f.z; h4[3] = (_Float16)f.w;
        int off = row * 512 + ((c4 * 8) ^ ((row & 7) << 4));
        *(f16x4*)(smem + off) = h4;
    }
    __syncthreads();

    // ---- GEMM: acc[ct][p] -> col = ct*16+(lane&15), row = wv*16+(lane>>4)*4+p
    f32x4 acc[16];
    #pragma unroll
    for (int ct = 0; ct < 16; ++ct) {
        float b = bias[ct * 16 + (lane & 15)];
        acc[ct] = f32x4{b, b, b, b};
    }

    const int arow  = wv * 16 + (lane & 15);
    const int swzA  = (arow & 7) << 4;
    const int abase = arow * 512;
    const int kgrp  = (lane >> 4) * 16;

    #pragma unroll
    for (int kt = 0; kt < 8; ++kt) {
        int kbyte = kt * 64 + kgrp;
        f16x8 a8 = *(const f16x8*)(smem + abase + (kbyte ^ swzA));
        #pragma unroll
        for (int ct = 0; ct < 16; ++ct) {
            f16x8 bh = ws[(kt * 16 + ct) * 64 + lane];
            f16x8 bl = ws[8192 + (kt * 16 + ct) * 64 + lane];
            acc[ct] = __builtin_amdgcn_mfma_f32_16x16x32_f16(a8, bh, acc[ct], 0, 0, 0);
            acc[ct] = __builtin_amdgcn_mfma_f32_16x16x32_f16(a8, bl, acc[ct], 0, 0, 0);
        }
    }

    // ---- row max per plane: 16 cts in-thread + DPP 16-lane reduce ----
    float M[4];
    #pragma unroll
    for (int p = 0; p < 4; ++p) {
        float m = acc[0][p];
        #pragma unroll
        for (int ct = 1; ct < 16; ++ct) m = fmaxf(m, acc[ct][p]);
        M[p] = row16_max(m);
    }

    // ---- q0 = E = exp2((mask-M)*C); le5 = (mask-M)*log2e (fp16, for z-recovery)
    f32x2 q2[8][4];
    f16x2 le5h[8][4];
    #pragma unroll
    for (int cc = 0; cc < 8; ++cc) {
        #pragma unroll
        for (int p = 0; p < 4; ++p) {
            float d0 = acc[2 * cc][p]     - M[p];
            float d1 = acc[2 * cc + 1][p] - M[p];
            q2[cc][p] = f32x2{__builtin_amdgcn_exp2f(d0 * EXP_C),
                              __builtin_amdgcn_exp2f(d1 * EXP_C)};
            le5h[cc][p] = f16x2{(_Float16)(d0 * LOG2E), (_Float16)(d1 * LOG2E)};
        }
    }

    // ---- 26 peeling steps on q = E*z^5:  S=sum(q); r=1-q/S; q *= r^5 ----
    const f32x2 one2 = f32x2{1.0f, 1.0f};
    #pragma unroll 1
    for (int it = 0; it < KSTEPS; ++it) {
        #pragma unroll
        for (int p = 0; p < 4; ++p) {
            f32x2 s01 = pk_add(pk_add(q2[0][p], q2[1][p]),
                               pk_add(q2[2][p], q2[3][p]));
            f32x2 s23 = pk_add(pk_add(q2[4][p], q2[5][p]),
                               pk_add(q2[6][p], q2[7][p]));
            f32x2 sv  = pk_add(s01, s23);
            float s   = row16_sum(sv.x + sv.y);
            s = fmaxf(s, 1e-30f);                      // rcp(0) guard
            float rinv = __builtin_amdgcn_rcpf(s);
            f32x2 nr = f32x2{-rinv, -rinv};
            #pragma unroll
            for (int cc = 0; cc < 8; ++cc) {
                f32x2 r  = pk_fma(q2[cc][p], nr, one2);  // 1 - q/S
                f32x2 r2 = pk_mul(r, r);
                f32x2 r4 = pk_mul(r2, r2);
                f32x2 r5 = pk_mul(r4, r);
                q2[cc][p] = pk_mul(q2[cc][p], r5);
            }
        }
    }

    // ---- out = f * z / (1-P);  z = exp2(0.2*log2(q) - le5) ----
    #pragma unroll
    for (int p = 0; p < 4; ++p) {
        int row = wv * 16 + (lane >> 4) * 4 + p;
        long long grow = n0 + row;
        if (grow < N) {
            int swz = (row & 7) << 4;
            float* orow = out + grow * 256;
            #pragma unroll
            for (int cc = 0; cc < 8; ++cc) {
                #pragma unroll
                for (int h = 0; h < 2; ++h) {
                    int col = (2 * cc + h) * 16 + (lane & 15);
                    float qv  = fmaxf(h ? q2[cc][p].y : q2[cc][p].x, 0.0f);
                    float le5 = (float)le5h[cc][p][h];
                    float zz  = __builtin_amdgcn_exp2f(
                        fmaf(__builtin_amdgcn_logf(qv), 0.2f, -le5));
                    int off = row * 512 + ((col * 2) ^ swz);
                    float fval = (float)(*(const _Float16*)(smem + off));
                    orow[col] = fval * (zz * INV_1MP);
                }
            }
        }
    }
}

extern "C" void kernel_launch(void* const* d_in, const int* in_sizes, int n_in,
                              void* d_out, int out_size, void* d_ws, size_t ws_size,
                              hipStream_t stream) {
    const float* feat = (const float*)d_in[0];
    const float* W    = (const float*)d_in[1];
    const float* bias = (const float*)d_in[2];
    float* out = (float*)d_out;
    int N = in_sizes[0] / DIMD;

    // 1) W -> frag-major fp16 hi/lo in workspace (256 KB)
    w_conv_kernel<<<32, 256, 0, stream>>>(W, (f16x8*)d_ws);

    // 2) fused mask-GEMM + 26-step peeling (q-form) + output
    int grid = (int)((N + MT - 1) / MT);
    sad_mfma_kernel<<<grid, BT, 0, stream>>>(feat, bias, (const f16x8*)d_ws, out, N);
}